// Round 9
// baseline (89.404 us; speedup 1.0000x reference)
//
#include <hip/hip_runtime.h>
#include <hip/hip_bf16.h>

// Shapes fixed by the reference: N=16384 rows, C=1024, b=4096 groups of 4.
#define BGRP 4096
#define CDIM 1024

typedef __attribute__((ext_vector_type(8))) short bf16x8;
typedef __attribute__((ext_vector_type(4))) float f32x4;
typedef __attribute__((ext_vector_type(4))) unsigned short u16x4;

__device__ __forceinline__ unsigned short f2bf(float x) {
    __hip_bfloat16 h = __float2bfloat16(x);
    unsigned short u;
    __builtin_memcpy(&u, &h, 2);
    return u;
}

__device__ __forceinline__ void gload16(const void* g, void* l) {
    __builtin_amdgcn_global_load_lds(
        (const __attribute__((address_space(1))) unsigned int*)g,
        (__attribute__((address_space(3))) unsigned int*)l, 16, 0, 0);
}

// d: 10 packed upper-tri dots (raw rows, order (0,0),(0,1)..(3,3))
// coef[i] = softmax_i(sum_j G_ij) * inv_norm_i   where G = normalized Gram
__device__ __forceinline__ void group_coefs(const float* d, float* coef) {
    float D[4][4];
    int c = 0;
    #pragma unroll
    for (int i = 0; i < 4; ++i)
        #pragma unroll
        for (int j = i; j < 4; ++j) { D[i][j] = d[c]; D[j][i] = d[c]; ++c; }
    float inv[4];
    #pragma unroll
    for (int i = 0; i < 4; ++i) inv[i] = 1.0f / fmaxf(sqrtf(D[i][i]), 1e-12f);
    float s[4];
    #pragma unroll
    for (int i = 0; i < 4; ++i) {
        float si = 0.f;
        #pragma unroll
        for (int j = 0; j < 4; ++j) si += D[i][j] * inv[i] * inv[j];
        s[i] = si;
    }
    float m = fmaxf(fmaxf(s[0], s[1]), fmaxf(s[2], s[3]));
    float e[4], se = 0.f;
    #pragma unroll
    for (int i = 0; i < 4; ++i) { e[i] = expf(s[i] - m); se += e[i]; }
    float rse = 1.0f / se;
    #pragma unroll
    for (int i = 0; i < 4; ++i) coef[i] = e[i] * rse * inv[i];
}

__device__ __forceinline__ float wave_allsum(float t) {
    t += __shfl_xor(t, 1, 64);
    t += __shfl_xor(t, 2, 64);
    t += __shfl_xor(t, 4, 64);
    t += __shfl_xor(t, 8, 64);
    t += __shfl_xor(t, 16, 64);
    t += __shfl_xor(t, 32, 64);
    return t;
}

// ---------------- Kernel A: group pooling, ONE WAVE per (group, input) -------
// Block = 4 waves = 2 groups x {x1-wave, x2-wave} (best-measured structure).
// ALL transient/global writes nontemporal -> x1/x2 stay L3-resident across
// replays. XCD-bijective blockIdx swizzle -> contiguous 16MB read slice/XCD.
__global__ __launch_bounds__(256, 4) void pool_kernel(
    const float* __restrict__ x1, const float* __restrict__ x2,
    float* __restrict__ out,
    unsigned short* __restrict__ p1b, unsigned short* __restrict__ p2b,
    float* __restrict__ diag, float* __restrict__ centerArr,
    float* __restrict__ zero8k)
{
    // XCD-bijective swizzle (2048 blocks, 2048 % 8 == 0)
    const int nwg = BGRP / 2;
    const int bid = (int)blockIdx.x;
    const int blk = (bid % 8) * (nwg / 8) + bid / 8;

    // fused zeroing of rowsum/colsum (2048 blocks x 4 = 8192 floats)
    if (threadIdx.x < 4)
        __builtin_nontemporal_store(0.f, &zero8k[blk * 4 + threadIdx.x]);

    __shared__ float plds[2][CDIM];   // pooled p1 of the block's two groups
    const int l    = threadIdx.x & 63;
    const int wv   = threadIdx.x >> 6;      // 0..3
    const int gi   = wv >> 1;               // group slot in block: 0,1
    const int isx2 = wv & 1;                // 0 -> x1, 1 -> x2
    const int g    = blk * 2 + gi;

    const float* __restrict__ x = isx2 ? x2 : x1;

    // ---- load: 16 float4 per lane (4 rows x 4 chunks), coalesced ------------
    float4 a[4][4];
    #pragma unroll
    for (int i = 0; i < 4; ++i)
        #pragma unroll
        for (int w = 0; w < 4; ++w)
            a[i][w] = reinterpret_cast<const float4*>(x)[(size_t)(4 * g + i) * 256 + w * 64 + l];

    // ---- Gram (10 upper-tri dots) + wave butterfly reduce -------------------
    float dd[10];
    {
        int c = 0;
        #pragma unroll
        for (int i = 0; i < 4; ++i)
            #pragma unroll
            for (int j = i; j < 4; ++j) {
                float s0 = 0.f;
                #pragma unroll
                for (int w = 0; w < 4; ++w)
                    s0 += a[i][w].x * a[j][w].x + a[i][w].y * a[j][w].y
                        + a[i][w].z * a[j][w].z + a[i][w].w * a[j][w].w;
                dd[c++] = s0;
            }
    }
    #pragma unroll
    for (int v = 0; v < 10; ++v) dd[v] = wave_allsum(dd[v]);

    float coef[4];
    group_coefs(dd, coef);

    // |q|^2 closed-form from Gram: n = c^T D c  (no extra reduction)
    float D[4][4];
    {
        int c = 0;
        #pragma unroll
        for (int i = 0; i < 4; ++i)
            #pragma unroll
            for (int j = i; j < 4; ++j) { D[i][j] = dd[c]; D[j][i] = dd[c]; ++c; }
    }
    float n = 0.f;
    #pragma unroll
    for (int i = 0; i < 4; ++i) {
        float ti = 0.f;
        #pragma unroll
        for (int j = 0; j < 4; ++j) ti += D[i][j] * coef[j];
        n += coef[i] * ti;
    }
    const float inv = 1.0f / fmaxf(sqrtf(n), 1e-12f);

    // ---- pooled + normalized vector; stores + LDS deposit -------------------
    float* pout = out + 1 + (size_t)(g + (isx2 ? BGRP : 0)) * CDIM;
    unsigned short* pb = isx2 ? (p2b ? p2b + (size_t)g * CDIM : nullptr)
                              : (p1b ? p1b + (size_t)g * CDIM : nullptr);

    float4 q[4];
    #pragma unroll
    for (int w = 0; w < 4; ++w) {
        float4 qq;
        qq.x = coef[0]*a[0][w].x + coef[1]*a[1][w].x + coef[2]*a[2][w].x + coef[3]*a[3][w].x;
        qq.y = coef[0]*a[0][w].y + coef[1]*a[1][w].y + coef[2]*a[2][w].y + coef[3]*a[3][w].y;
        qq.z = coef[0]*a[0][w].z + coef[1]*a[1][w].z + coef[2]*a[2][w].z + coef[3]*a[3][w].z;
        qq.w = coef[0]*a[0][w].w + coef[1]*a[1][w].w + coef[2]*a[2][w].w + coef[3]*a[3][w].w;
        qq.x *= inv; qq.y *= inv; qq.z *= inv; qq.w *= inv;
        q[w] = qq;
    }

    // x1-waves deposit p1 into LDS first (shortens the barrier wait)
    if (!isx2) {
        #pragma unroll
        for (int w = 0; w < 4; ++w)
            *reinterpret_cast<float4*>(&plds[gi][w * 256 + l * 4]) = q[w];
    }

    #pragma unroll
    for (int w = 0; w < 4; ++w) {
        const int e = w * 256 + l * 4;
        // dense 16B/lane streaming store via ext-vector (builtin-compatible)
        f32x4 qv;
        qv[0] = q[w].x; qv[1] = q[w].y; qv[2] = q[w].z; qv[3] = q[w].w;
        __builtin_nontemporal_store(qv, reinterpret_cast<f32x4*>(pout + e));
        if (pb != nullptr) {
            u16x4 wb;
            wb[0] = f2bf(q[w].x); wb[1] = f2bf(q[w].y);
            wb[2] = f2bf(q[w].z); wb[3] = f2bf(q[w].w);
            // NT: don't evict x1/x2 from L3 (sim refetches 16MB once, cheap)
            __builtin_nontemporal_store(wb, reinterpret_cast<u16x4*>(pb + e));
        }
    }

    __syncthreads();

    // x2-waves: dp = p1 . p2 ; diag & center (exact fp32)
    if (isx2) {
        float dp = 0.f;
        #pragma unroll
        for (int w = 0; w < 4; ++w) {
            float4 p1v = *reinterpret_cast<const float4*>(&plds[gi][w * 256 + l * 4]);
            dp += p1v.x * q[w].x + p1v.y * q[w].y + p1v.z * q[w].z + p1v.w * q[w].w;
        }
        dp = wave_allsum(dp);
        if (l == 0) {
            __builtin_nontemporal_store(dp, &diag[g]);
            __builtin_nontemporal_store(sqrtf(fmaxf(2.0f - 2.0f * dp, 0.0f)),
                                        &centerArr[g]);   // ||p1-p2||, |p|=1
        }
    }
}

// ---------------- Kernel B: sim = p1 @ p2^T, m97-style LDS-staged MFMA -------
// (proven R2 structure: 128x128 tile, BK=64, 4 waves 2x2, T2 swizzle via
// pre-swizzled global source + XOR'd ds_read column.)
__global__ __launch_bounds__(256, 4) void sim_lds_kernel(
    const unsigned short* __restrict__ p1b, const unsigned short* __restrict__ p2b,
    float* __restrict__ rowsum, float* __restrict__ colsum)
{
    __shared__ __align__(16) unsigned char lds[32768];   // A: [0,16K)  B: [16K,32K)
    const int tid  = threadIdx.x;
    const int lane = tid & 63;
    const int wid  = tid >> 6;
    const int wm = wid >> 1, wn = wid & 1;
    const int row0 = blockIdx.y * 128;
    const int col0 = blockIdx.x * 128;
    const int lr  = lane & 15;     // M/N index within 16x16 fragment
    const int lkb = lane >> 4;     // k-subgroup 0..3

    // staging geometry: each 1KB chunk = 8 rows x 128B; lane covers
    // physical (row = chunk*8 + lane/8, colbyte = (lane&7)*16).
    // Inverse-swizzled source col: 16*((lane&7) ^ (lane/8)).
    const int srow = lane >> 3;
    const int scol = ((lane & 7) ^ srow) << 4;
    const int ch0  = wid * 4;      // 4 chunks per wave per operand

    f32x4 acc[4][4];
    #pragma unroll
    for (int mi = 0; mi < 4; ++mi)
        #pragma unroll
        for (int ni = 0; ni < 4; ++ni) {
            acc[mi][ni][0] = 0.f; acc[mi][ni][1] = 0.f;
            acc[mi][ni][2] = 0.f; acc[mi][ni][3] = 0.f;
        }

    const char* A = (const char*)p1b;   // row stride 2048 B
    const char* B = (const char*)p2b;

    for (int kt = 0; kt < 16; ++kt) {
        const size_t kbyte = (size_t)kt * 128;
        #pragma unroll
        for (int c = 0; c < 4; ++c) {
            const int chunk = ch0 + c;
            const int r = chunk * 8 + srow;
            gload16(A + (size_t)(row0 + r) * 2048 + kbyte + scol, lds + chunk * 1024);
            gload16(B + (size_t)(col0 + r) * 2048 + kbyte + scol, lds + 16384 + chunk * 1024);
        }
        __syncthreads();   // drains vmcnt -> staged data visible

        #pragma unroll
        for (int ks = 0; ks < 2; ++ks) {
            bf16x8 af[4], bg[4];
            const int cbase = (ks * 64 + lkb * 16) ^ ((lr & 7) << 4);
            #pragma unroll
            for (int i = 0; i < 4; ++i) {
                const int ra = wm * 64 + i * 16 + lr;
                const int rb = wn * 64 + i * 16 + lr;
                af[i] = *reinterpret_cast<const bf16x8*>(lds + ra * 128 + cbase);
                bg[i] = *reinterpret_cast<const bf16x8*>(lds + 16384 + rb * 128 + cbase);
            }
            #pragma unroll
            for (int mi = 0; mi < 4; ++mi)
                #pragma unroll
                for (int ni = 0; ni < 4; ++ni)
                    acc[mi][ni] = __builtin_amdgcn_mfma_f32_16x16x32_bf16(
                        af[mi], bg[ni], acc[mi][ni], 0, 0, 0);
        }
        __syncthreads();   // reads done before next stage overwrites
    }

    // exp() and row/col partial sums.
    // D layout: row = mi*16 + lkb*4 + r (r = reg), col = ni*16 + lr.
    float rs[4][4];
    float cs[4] = {0.f, 0.f, 0.f, 0.f};
    #pragma unroll
    for (int mi = 0; mi < 4; ++mi)
        #pragma unroll
        for (int r = 0; r < 4; ++r) rs[mi][r] = 0.f;

    #pragma unroll
    for (int mi = 0; mi < 4; ++mi)
        #pragma unroll
        for (int ni = 0; ni < 4; ++ni)
            #pragma unroll
            for (int r = 0; r < 4; ++r) {
                float e = __expf(acc[mi][ni][r]);
                rs[mi][r] += e;
                cs[ni] += e;
            }

    const int wrow0 = row0 + wm * 64;
    const int wcol0 = col0 + wn * 64;
    #pragma unroll
    for (int mi = 0; mi < 4; ++mi)
        #pragma unroll
        for (int r = 0; r < 4; ++r) {
            float v = rs[mi][r];
            v += __shfl_xor(v, 1, 64);
            v += __shfl_xor(v, 2, 64);
            v += __shfl_xor(v, 4, 64);
            v += __shfl_xor(v, 8, 64);
            if (lr == 0) atomicAdd(&rowsum[wrow0 + mi * 16 + lkb * 4 + r], v);
        }
    #pragma unroll
    for (int ni = 0; ni < 4; ++ni) {
        float v = cs[ni];
        v += __shfl_xor(v, 16, 64);
        v += __shfl_xor(v, 32, 64);
        if (lkb == 0) atomicAdd(&colsum[wcol0 + ni * 16 + lr], v);
    }
}

// ---------------- fallback sim (no ws): read fp32 p1/p2 from out -------------
__device__ __forceinline__ bf16x8 frag_from_f32(const float* p) {
    bf16x8 r;
    #pragma unroll
    for (int i = 0; i < 8; ++i) {
        unsigned int b = __float_as_uint(p[i]);
        b += 0x7fffu + ((b >> 16) & 1u);   // RNE to bf16
        r[i] = (short)(b >> 16);
    }
    return r;
}

__global__ __launch_bounds__(256) void sim_fallback_kernel(
    const float* __restrict__ p1f, const float* __restrict__ p2f,
    float* __restrict__ rowsum, float* __restrict__ colsum)
{
    const int lane = threadIdx.x & 63;
    const int wid  = threadIdx.x >> 6;
    const int wm = wid >> 1, wn = wid & 1;
    const int row0 = blockIdx.y * 128 + wm * 64;
    const int col0 = blockIdx.x * 128 + wn * 64;
    const int lr  = lane & 15;
    const int lkb = lane >> 4;
    const int lk  = lkb * 8;

    f32x4 acc[4][4];
    #pragma unroll
    for (int mi = 0; mi < 4; ++mi)
        #pragma unroll
        for (int ni = 0; ni < 4; ++ni) {
            acc[mi][ni][0] = 0.f; acc[mi][ni][1] = 0.f;
            acc[mi][ni][2] = 0.f; acc[mi][ni][3] = 0.f;
        }

    const size_t abase = (size_t)(row0 + lr) * CDIM + lk;
    const size_t bbase = (size_t)(col0 + lr) * CDIM + lk;

    for (int k = 0; k < CDIM; k += 32) {
        bf16x8 af[4], bfr[4];
        #pragma unroll
        for (int i = 0; i < 4; ++i) {
            af[i]  = frag_from_f32(p1f + abase + (size_t)i * 16 * CDIM + k);
            bfr[i] = frag_from_f32(p2f + bbase + (size_t)i * 16 * CDIM + k);
        }
        #pragma unroll
        for (int mi = 0; mi < 4; ++mi)
            #pragma unroll
            for (int ni = 0; ni < 4; ++ni)
                acc[mi][ni] = __builtin_amdgcn_mfma_f32_16x16x32_bf16(
                    af[mi], bfr[ni], acc[mi][ni], 0, 0, 0);
    }

    float rs[4][4];
    float cs[4] = {0.f, 0.f, 0.f, 0.f};
    #pragma unroll
    for (int mi = 0; mi < 4; ++mi)
        #pragma unroll
        for (int r = 0; r < 4; ++r) rs[mi][r] = 0.f;

    #pragma unroll
    for (int mi = 0; mi < 4; ++mi)
        #pragma unroll
        for (int ni = 0; ni < 4; ++ni)
            #pragma unroll
            for (int r = 0; r < 4; ++r) {
                float e = __expf(acc[mi][ni][r]);
                rs[mi][r] += e;
                cs[ni] += e;
            }

    #pragma unroll
    for (int mi = 0; mi < 4; ++mi)
        #pragma unroll
        for (int r = 0; r < 4; ++r) {
            float v = rs[mi][r];
            v += __shfl_xor(v, 1, 64);
            v += __shfl_xor(v, 2, 64);
            v += __shfl_xor(v, 4, 64);
            v += __shfl_xor(v, 8, 64);
            if (lr == 0) atomicAdd(&rowsum[row0 + mi * 16 + lkb * 4 + r], v);
        }
    #pragma unroll
    for (int ni = 0; ni < 4; ++ni) {
        float v = cs[ni];
        v += __shfl_xor(v, 16, 64);
        v += __shfl_xor(v, 32, 64);
        if (lkb == 0) atomicAdd(&colsum[col0 + ni * 16 + lr], v);
    }
}

// ---------------- Kernel C: final scalar loss ---------------------------------
__global__ __launch_bounds__(256) void loss_kernel(
    const float* __restrict__ rowsum, const float* __restrict__ colsum,
    const float* __restrict__ diag, const float* __restrict__ centerArr,
    float* __restrict__ out)
{
    float part = 0.f;
    for (int i = threadIdx.x; i < BGRP; i += 256)
        part += __logf(rowsum[i]) + __logf(colsum[i]) - 2.0f * diag[i] + centerArr[i];
    #pragma unroll
    for (int off = 32; off > 0; off >>= 1) part += __shfl_down(part, off, 64);
    __shared__ float l4[4];
    if ((threadIdx.x & 63) == 0) l4[threadIdx.x >> 6] = part;
    __syncthreads();
    if (threadIdx.x == 0)
        out[0] = (l4[0] + l4[1] + l4[2] + l4[3]) * (1.0f / (float)BGRP);
}

// ---------------- launch ------------------------------------------------------
extern "C" void kernel_launch(void* const* d_in, const int* in_sizes, int n_in,
                              void* d_out, int out_size, void* d_ws, size_t ws_size,
                              hipStream_t stream)
{
    const float* x1 = (const float*)d_in[0];
    const float* x2 = (const float*)d_in[1];
    float* out = (float*)d_out;

    float* rowsum    = (float*)d_ws;            // 4096
    float* colsum    = rowsum + BGRP;           // 4096 (contiguous with rowsum)
    float* diag      = colsum + BGRP;           // 4096
    float* centerArr = diag + BGRP;             // 4096
    const size_t head_floats = 4 * (size_t)BGRP;       // 64 KB, 16B aligned
    unsigned short* p1b = (unsigned short*)((char*)d_ws + head_floats * sizeof(float));
    unsigned short* p2b = p1b + (size_t)BGRP * CDIM;
    const size_t need = head_floats * sizeof(float) + (size_t)2 * BGRP * CDIM * sizeof(unsigned short);
    const bool use_ws = (ws_size >= need);

    pool_kernel<<<BGRP / 2, 256, 0, stream>>>(x1, x2, out,
                                              use_ws ? p1b : nullptr,
                                              use_ws ? p2b : nullptr,
                                              diag, centerArr, rowsum);

    if (use_ws) {
        dim3 gridB(BGRP / 128, BGRP / 128);
        sim_lds_kernel<<<gridB, 256, 0, stream>>>(p1b, p2b, rowsum, colsum);
    } else {
        dim3 gridB(BGRP / 128, BGRP / 128);
        sim_fallback_kernel<<<gridB, 256, 0, stream>>>(out + 1, out + 1 + (size_t)BGRP * CDIM,
                                                       rowsum, colsum);
    }

    loss_kernel<<<1, 256, 0, stream>>>(rowsum, colsum, diag, centerArr, out);
}

// Round 10
// 81.460 us; speedup vs baseline: 1.0975x; 1.0975x over previous
//
#include <hip/hip_runtime.h>
#include <hip/hip_bf16.h>

// Shapes fixed by the reference: N=16384 rows, C=1024, b=4096 groups of 4.
#define BGRP 4096
#define CDIM 1024

typedef __attribute__((ext_vector_type(8))) short bf16x8;
typedef __attribute__((ext_vector_type(4))) float f32x4;
typedef __attribute__((ext_vector_type(4))) unsigned short u16x4;

__device__ __forceinline__ unsigned short f2bf(float x) {
    __hip_bfloat16 h = __float2bfloat16(x);
    unsigned short u;
    __builtin_memcpy(&u, &h, 2);
    return u;
}

__device__ __forceinline__ void gload16(const void* g, void* l) {
    __builtin_amdgcn_global_load_lds(
        (const __attribute__((address_space(1))) unsigned int*)g,
        (__attribute__((address_space(3))) unsigned int*)l, 16, 0, 0);
}

// d: 10 packed upper-tri dots (raw rows, order (0,0),(0,1)..(3,3))
// coef[i] = softmax_i(sum_j G_ij) * inv_norm_i   where G = normalized Gram
__device__ __forceinline__ void group_coefs(const float* d, float* coef) {
    float D[4][4];
    int c = 0;
    #pragma unroll
    for (int i = 0; i < 4; ++i)
        #pragma unroll
        for (int j = i; j < 4; ++j) { D[i][j] = d[c]; D[j][i] = d[c]; ++c; }
    float inv[4];
    #pragma unroll
    for (int i = 0; i < 4; ++i) inv[i] = 1.0f / fmaxf(sqrtf(D[i][i]), 1e-12f);
    float s[4];
    #pragma unroll
    for (int i = 0; i < 4; ++i) {
        float si = 0.f;
        #pragma unroll
        for (int j = 0; j < 4; ++j) si += D[i][j] * inv[i] * inv[j];
        s[i] = si;
    }
    float m = fmaxf(fmaxf(s[0], s[1]), fmaxf(s[2], s[3]));
    float e[4], se = 0.f;
    #pragma unroll
    for (int i = 0; i < 4; ++i) { e[i] = expf(s[i] - m); se += e[i]; }
    float rse = 1.0f / se;
    #pragma unroll
    for (int i = 0; i < 4; ++i) coef[i] = e[i] * rse * inv[i];
}

__device__ __forceinline__ float wave_allsum(float t) {
    t += __shfl_xor(t, 1, 64);
    t += __shfl_xor(t, 2, 64);
    t += __shfl_xor(t, 4, 64);
    t += __shfl_xor(t, 8, 64);
    t += __shfl_xor(t, 16, 64);
    t += __shfl_xor(t, 32, 64);
    return t;
}

// ---------------- Kernel A: group pooling, ONE WAVE per (group, input) -------
// Block = 4 waves = 2 groups x {x1-wave, x2-wave} (best-measured structure).
// Wave-synchronous compute; one barrier for the p1/p2 pairing via LDS.
// fp32 p-outputs: ONE nontemporal dwordx4 store per lane; bf16 staging CACHED
// (sim re-reads it from L2/L3 -- R9 proved NT here regresses).
__global__ __launch_bounds__(256, 4) void pool_kernel(
    const float* __restrict__ x1, const float* __restrict__ x2,
    float* __restrict__ out,
    unsigned short* __restrict__ p1b, unsigned short* __restrict__ p2b,
    float* __restrict__ diag, float* __restrict__ centerArr,
    float* __restrict__ zero8k)
{
    // fused zeroing of rowsum/colsum (2048 blocks x 4 = 8192 floats)
    if (threadIdx.x < 4)
        zero8k[blockIdx.x * 4 + threadIdx.x] = 0.f;

    __shared__ float plds[2][CDIM];   // pooled p1 of the block's two groups
    const int l    = threadIdx.x & 63;
    const int wv   = threadIdx.x >> 6;      // 0..3
    const int gi   = wv >> 1;               // group slot in block: 0,1
    const int isx2 = wv & 1;                // 0 -> x1, 1 -> x2
    const int g    = blockIdx.x * 2 + gi;

    const float* __restrict__ x = isx2 ? x2 : x1;

    // ---- load: 16 float4 per lane (4 rows x 4 chunks), coalesced ------------
    float4 a[4][4];
    #pragma unroll
    for (int i = 0; i < 4; ++i)
        #pragma unroll
        for (int w = 0; w < 4; ++w)
            a[i][w] = reinterpret_cast<const float4*>(x)[(size_t)(4 * g + i) * 256 + w * 64 + l];

    // ---- Gram (10 upper-tri dots) + wave butterfly reduce -------------------
    float dd[10];
    {
        int c = 0;
        #pragma unroll
        for (int i = 0; i < 4; ++i)
            #pragma unroll
            for (int j = i; j < 4; ++j) {
                float s0 = 0.f;
                #pragma unroll
                for (int w = 0; w < 4; ++w)
                    s0 += a[i][w].x * a[j][w].x + a[i][w].y * a[j][w].y
                        + a[i][w].z * a[j][w].z + a[i][w].w * a[j][w].w;
                dd[c++] = s0;
            }
    }
    #pragma unroll
    for (int v = 0; v < 10; ++v) dd[v] = wave_allsum(dd[v]);

    float coef[4];
    group_coefs(dd, coef);

    // |q|^2 closed-form from Gram: n = c^T D c  (no extra reduction)
    float D[4][4];
    {
        int c = 0;
        #pragma unroll
        for (int i = 0; i < 4; ++i)
            #pragma unroll
            for (int j = i; j < 4; ++j) { D[i][j] = dd[c]; D[j][i] = dd[c]; ++c; }
    }
    float n = 0.f;
    #pragma unroll
    for (int i = 0; i < 4; ++i) {
        float ti = 0.f;
        #pragma unroll
        for (int j = 0; j < 4; ++j) ti += D[i][j] * coef[j];
        n += coef[i] * ti;
    }
    const float inv = 1.0f / fmaxf(sqrtf(n), 1e-12f);

    // ---- pooled + normalized vector; stores + LDS deposit -------------------
    float* pout = out + 1 + (size_t)(g + (isx2 ? BGRP : 0)) * CDIM;
    unsigned short* pb = isx2 ? (p2b ? p2b + (size_t)g * CDIM : nullptr)
                              : (p1b ? p1b + (size_t)g * CDIM : nullptr);

    float4 q[4];
    #pragma unroll
    for (int w = 0; w < 4; ++w) {
        float4 qq;
        qq.x = coef[0]*a[0][w].x + coef[1]*a[1][w].x + coef[2]*a[2][w].x + coef[3]*a[3][w].x;
        qq.y = coef[0]*a[0][w].y + coef[1]*a[1][w].y + coef[2]*a[2][w].y + coef[3]*a[3][w].y;
        qq.z = coef[0]*a[0][w].z + coef[1]*a[1][w].z + coef[2]*a[2][w].z + coef[3]*a[3][w].z;
        qq.w = coef[0]*a[0][w].w + coef[1]*a[1][w].w + coef[2]*a[2][w].w + coef[3]*a[3][w].w;
        qq.x *= inv; qq.y *= inv; qq.z *= inv; qq.w *= inv;
        q[w] = qq;
    }

    // x1-waves deposit p1 into LDS first (shortens the barrier wait)
    if (!isx2) {
        #pragma unroll
        for (int w = 0; w < 4; ++w)
            *reinterpret_cast<float4*>(&plds[gi][w * 256 + l * 4]) = q[w];
    }

    #pragma unroll
    for (int w = 0; w < 4; ++w) {
        const int e = w * 256 + l * 4;
        // dense 16B/lane streaming store via ext-vector (builtin-compatible)
        f32x4 qv;
        qv[0] = q[w].x; qv[1] = q[w].y; qv[2] = q[w].z; qv[3] = q[w].w;
        __builtin_nontemporal_store(qv, reinterpret_cast<f32x4*>(pout + e));
        if (pb != nullptr) {
            u16x4 wb;
            wb[0] = f2bf(q[w].x); wb[1] = f2bf(q[w].y);
            wb[2] = f2bf(q[w].z); wb[3] = f2bf(q[w].w);
            *reinterpret_cast<u16x4*>(pb + e) = wb;   // cached: sim re-reads
        }
    }

    __syncthreads();

    // x2-waves: dp = p1 . p2 ; diag & center (exact fp32)
    if (isx2) {
        float dp = 0.f;
        #pragma unroll
        for (int w = 0; w < 4; ++w) {
            float4 p1v = *reinterpret_cast<const float4*>(&plds[gi][w * 256 + l * 4]);
            dp += p1v.x * q[w].x + p1v.y * q[w].y + p1v.z * q[w].z + p1v.w * q[w].w;
        }
        dp = wave_allsum(dp);
        if (l == 0) {
            diag[g] = dp;
            centerArr[g] = sqrtf(fmaxf(2.0f - 2.0f * dp, 0.0f));   // |p|=1
        }
    }
}

// ---------------- Kernel B: sim = p1 @ p2^T, m97-style LDS-staged MFMA -------
// (proven R2 structure: 128x128 tile, BK=64, 4 waves 2x2, T2 swizzle via
// pre-swizzled global source + XOR'd ds_read column.)
__global__ __launch_bounds__(256, 4) void sim_lds_kernel(
    const unsigned short* __restrict__ p1b, const unsigned short* __restrict__ p2b,
    float* __restrict__ rowsum, float* __restrict__ colsum)
{
    __shared__ __align__(16) unsigned char lds[32768];   // A: [0,16K)  B: [16K,32K)
    const int tid  = threadIdx.x;
    const int lane = tid & 63;
    const int wid  = tid >> 6;
    const int wm = wid >> 1, wn = wid & 1;
    const int row0 = blockIdx.y * 128;
    const int col0 = blockIdx.x * 128;
    const int lr  = lane & 15;     // M/N index within 16x16 fragment
    const int lkb = lane >> 4;     // k-subgroup 0..3

    // staging geometry: each 1KB chunk = 8 rows x 128B; lane covers
    // physical (row = chunk*8 + lane/8, colbyte = (lane&7)*16).
    // Inverse-swizzled source col: 16*((lane&7) ^ (lane/8)).
    const int srow = lane >> 3;
    const int scol = ((lane & 7) ^ srow) << 4;
    const int ch0  = wid * 4;      // 4 chunks per wave per operand

    f32x4 acc[4][4];
    #pragma unroll
    for (int mi = 0; mi < 4; ++mi)
        #pragma unroll
        for (int ni = 0; ni < 4; ++ni) {
            acc[mi][ni][0] = 0.f; acc[mi][ni][1] = 0.f;
            acc[mi][ni][2] = 0.f; acc[mi][ni][3] = 0.f;
        }

    const char* A = (const char*)p1b;   // row stride 2048 B
    const char* B = (const char*)p2b;

    for (int kt = 0; kt < 16; ++kt) {
        const size_t kbyte = (size_t)kt * 128;
        #pragma unroll
        for (int c = 0; c < 4; ++c) {
            const int chunk = ch0 + c;
            const int r = chunk * 8 + srow;
            gload16(A + (size_t)(row0 + r) * 2048 + kbyte + scol, lds + chunk * 1024);
            gload16(B + (size_t)(col0 + r) * 2048 + kbyte + scol, lds + 16384 + chunk * 1024);
        }
        __syncthreads();   // drains vmcnt -> staged data visible

        #pragma unroll
        for (int ks = 0; ks < 2; ++ks) {
            bf16x8 af[4], bg[4];
            const int cbase = (ks * 64 + lkb * 16) ^ ((lr & 7) << 4);
            #pragma unroll
            for (int i = 0; i < 4; ++i) {
                const int ra = wm * 64 + i * 16 + lr;
                const int rb = wn * 64 + i * 16 + lr;
                af[i] = *reinterpret_cast<const bf16x8*>(lds + ra * 128 + cbase);
                bg[i] = *reinterpret_cast<const bf16x8*>(lds + 16384 + rb * 128 + cbase);
            }
            #pragma unroll
            for (int mi = 0; mi < 4; ++mi)
                #pragma unroll
                for (int ni = 0; ni < 4; ++ni)
                    acc[mi][ni] = __builtin_amdgcn_mfma_f32_16x16x32_bf16(
                        af[mi], bg[ni], acc[mi][ni], 0, 0, 0);
        }
        __syncthreads();   // reads done before next stage overwrites
    }

    // exp() and row/col partial sums.
    // D layout: row = mi*16 + lkb*4 + r (r = reg), col = ni*16 + lr.
    float rs[4][4];
    float cs[4] = {0.f, 0.f, 0.f, 0.f};
    #pragma unroll
    for (int mi = 0; mi < 4; ++mi)
        #pragma unroll
        for (int r = 0; r < 4; ++r) rs[mi][r] = 0.f;

    #pragma unroll
    for (int mi = 0; mi < 4; ++mi)
        #pragma unroll
        for (int ni = 0; ni < 4; ++ni)
            #pragma unroll
            for (int r = 0; r < 4; ++r) {
                float e = __expf(acc[mi][ni][r]);
                rs[mi][r] += e;
                cs[ni] += e;
            }

    const int wrow0 = row0 + wm * 64;
    const int wcol0 = col0 + wn * 64;
    #pragma unroll
    for (int mi = 0; mi < 4; ++mi)
        #pragma unroll
        for (int r = 0; r < 4; ++r) {
            float v = rs[mi][r];
            v += __shfl_xor(v, 1, 64);
            v += __shfl_xor(v, 2, 64);
            v += __shfl_xor(v, 4, 64);
            v += __shfl_xor(v, 8, 64);
            if (lr == 0) atomicAdd(&rowsum[wrow0 + mi * 16 + lkb * 4 + r], v);
        }
    #pragma unroll
    for (int ni = 0; ni < 4; ++ni) {
        float v = cs[ni];
        v += __shfl_xor(v, 16, 64);
        v += __shfl_xor(v, 32, 64);
        if (lkb == 0) atomicAdd(&colsum[wcol0 + ni * 16 + lr], v);
    }
}

// ---------------- fallback sim (no ws): read fp32 p1/p2 from out -------------
__device__ __forceinline__ bf16x8 frag_from_f32(const float* p) {
    bf16x8 r;
    #pragma unroll
    for (int i = 0; i < 8; ++i) {
        unsigned int b = __float_as_uint(p[i]);
        b += 0x7fffu + ((b >> 16) & 1u);   // RNE to bf16
        r[i] = (short)(b >> 16);
    }
    return r;
}

__global__ __launch_bounds__(256) void sim_fallback_kernel(
    const float* __restrict__ p1f, const float* __restrict__ p2f,
    float* __restrict__ rowsum, float* __restrict__ colsum)
{
    const int lane = threadIdx.x & 63;
    const int wid  = threadIdx.x >> 6;
    const int wm = wid >> 1, wn = wid & 1;
    const int row0 = blockIdx.y * 128 + wm * 64;
    const int col0 = blockIdx.x * 128 + wn * 64;
    const int lr  = lane & 15;
    const int lkb = lane >> 4;
    const int lk  = lkb * 8;

    f32x4 acc[4][4];
    #pragma unroll
    for (int mi = 0; mi < 4; ++mi)
        #pragma unroll
        for (int ni = 0; ni < 4; ++ni) {
            acc[mi][ni][0] = 0.f; acc[mi][ni][1] = 0.f;
            acc[mi][ni][2] = 0.f; acc[mi][ni][3] = 0.f;
        }

    const size_t abase = (size_t)(row0 + lr) * CDIM + lk;
    const size_t bbase = (size_t)(col0 + lr) * CDIM + lk;

    for (int k = 0; k < CDIM; k += 32) {
        bf16x8 af[4], bfr[4];
        #pragma unroll
        for (int i = 0; i < 4; ++i) {
            af[i]  = frag_from_f32(p1f + abase + (size_t)i * 16 * CDIM + k);
            bfr[i] = frag_from_f32(p2f + bbase + (size_t)i * 16 * CDIM + k);
        }
        #pragma unroll
        for (int mi = 0; mi < 4; ++mi)
            #pragma unroll
            for (int ni = 0; ni < 4; ++ni)
                acc[mi][ni] = __builtin_amdgcn_mfma_f32_16x16x32_bf16(
                    af[mi], bfr[ni], acc[mi][ni], 0, 0, 0);
    }

    float rs[4][4];
    float cs[4] = {0.f, 0.f, 0.f, 0.f};
    #pragma unroll
    for (int mi = 0; mi < 4; ++mi)
        #pragma unroll
        for (int r = 0; r < 4; ++r) rs[mi][r] = 0.f;

    #pragma unroll
    for (int mi = 0; mi < 4; ++mi)
        #pragma unroll
        for (int ni = 0; ni < 4; ++ni)
            #pragma unroll
            for (int r = 0; r < 4; ++r) {
                float e = __expf(acc[mi][ni][r]);
                rs[mi][r] += e;
                cs[ni] += e;
            }

    #pragma unroll
    for (int mi = 0; mi < 4; ++mi)
        #pragma unroll
        for (int r = 0; r < 4; ++r) {
            float v = rs[mi][r];
            v += __shfl_xor(v, 1, 64);
            v += __shfl_xor(v, 2, 64);
            v += __shfl_xor(v, 4, 64);
            v += __shfl_xor(v, 8, 64);
            if (lr == 0) atomicAdd(&rowsum[row0 + mi * 16 + lkb * 4 + r], v);
        }
    #pragma unroll
    for (int ni = 0; ni < 4; ++ni) {
        float v = cs[ni];
        v += __shfl_xor(v, 16, 64);
        v += __shfl_xor(v, 32, 64);
        if (lkb == 0) atomicAdd(&colsum[col0 + ni * 16 + lr], v);
    }
}

// ---------------- Kernel C: final scalar loss ---------------------------------
__global__ __launch_bounds__(256) void loss_kernel(
    const float* __restrict__ rowsum, const float* __restrict__ colsum,
    const float* __restrict__ diag, const float* __restrict__ centerArr,
    float* __restrict__ out)
{
    float part = 0.f;
    for (int i = threadIdx.x; i < BGRP; i += 256)
        part += __logf(rowsum[i]) + __logf(colsum[i]) - 2.0f * diag[i] + centerArr[i];
    #pragma unroll
    for (int off = 32; off > 0; off >>= 1) part += __shfl_down(part, off, 64);
    __shared__ float l4[4];
    if ((threadIdx.x & 63) == 0) l4[threadIdx.x >> 6] = part;
    __syncthreads();
    if (threadIdx.x == 0)
        out[0] = (l4[0] + l4[1] + l4[2] + l4[3]) * (1.0f / (float)BGRP);
}

// ---------------- launch ------------------------------------------------------
extern "C" void kernel_launch(void* const* d_in, const int* in_sizes, int n_in,
                              void* d_out, int out_size, void* d_ws, size_t ws_size,
                              hipStream_t stream)
{
    const float* x1 = (const float*)d_in[0];
    const float* x2 = (const float*)d_in[1];
    float* out = (float*)d_out;

    float* rowsum    = (float*)d_ws;            // 4096
    float* colsum    = rowsum + BGRP;           // 4096 (contiguous with rowsum)
    float* diag      = colsum + BGRP;           // 4096
    float* centerArr = diag + BGRP;             // 4096
    const size_t head_floats = 4 * (size_t)BGRP;       // 64 KB, 16B aligned
    unsigned short* p1b = (unsigned short*)((char*)d_ws + head_floats * sizeof(float));
    unsigned short* p2b = p1b + (size_t)BGRP * CDIM;
    const size_t need = head_floats * sizeof(float) + (size_t)2 * BGRP * CDIM * sizeof(unsigned short);
    const bool use_ws = (ws_size >= need);

    pool_kernel<<<BGRP / 2, 256, 0, stream>>>(x1, x2, out,
                                              use_ws ? p1b : nullptr,
                                              use_ws ? p2b : nullptr,
                                              diag, centerArr, rowsum);

    if (use_ws) {
        dim3 gridB(BGRP / 128, BGRP / 128);
        sim_lds_kernel<<<gridB, 256, 0, stream>>>(p1b, p2b, rowsum, colsum);
    } else {
        dim3 gridB(BGRP / 128, BGRP / 128);
        sim_fallback_kernel<<<gridB, 256, 0, stream>>>(out + 1, out + 1 + (size_t)BGRP * CDIM,
                                                       rowsum, colsum);
    }

    loss_kernel<<<1, 256, 0, stream>>>(rowsum, colsum, diag, centerArr, out);
}